// Round 1
// baseline (1524.655 us; speedup 1.0000x reference)
//
#include <hip/hip_runtime.h>

#define NEG_SLOPE 0.2f
#define EPSV 1e-16f
#define NHEADS 8
#define NCH 16

// S1[h] = sum_c W1[h*16+c] * att_src1[h*16+c]; D1 likewise with att_dst1.
__global__ void gat_setup_kernel(const float* __restrict__ W1,
                                 const float* __restrict__ as1,
                                 const float* __restrict__ ad1,
                                 float* __restrict__ S1, float* __restrict__ D1) {
    int h = threadIdx.x;
    if (h < NHEADS) {
        float s = 0.f, d = 0.f;
        for (int c = 0; c < NCH; ++c) {
            float w = W1[h * NCH + c];
            s += w * as1[h * NCH + c];
            d += w * ad1[h * NCH + c];
        }
        S1[h] = s;
        D1[h] = d;
    }
}

// Layer 1 edge pass: e[h] = leaky(x[s]*S1[h] + x[d]*D1[h]); accumulate
// denom1[d,h] += exp(e), num1[d,h] += exp(e)*x[s].
__global__ __launch_bounds__(256) void gat_edge1_kernel(
        const int* __restrict__ ei, int E, const float* __restrict__ x,
        const float* __restrict__ S1, const float* __restrict__ D1,
        float* __restrict__ denom1, float* __restrict__ num1) {
    int i = blockIdx.x * blockDim.x + threadIdx.x;
    if (i >= E) return;
    int s = ei[i];
    int d = ei[E + i];
    float xs = x[s];
    float xd = x[d];
#pragma unroll
    for (int h = 0; h < NHEADS; ++h) {
        float e = xs * S1[h] + xd * D1[h];
        e = e > 0.f ? e : NEG_SLOPE * e;
        float ex = __expf(e);
        atomicAdd(&denom1[(size_t)d * NHEADS + h], ex);
        atomicAdd(&num1[(size_t)d * NHEADS + h], ex * xs);
    }
}

// Layer 1 node pass: fold in self-loop, z = num/(denom+eps),
// h_feat[k] = elu(W1[k]*z[h(k)] + b1[k]), h2[n] = sum_k h_feat[k]*W2[k].
__global__ __launch_bounds__(256) void gat_node1_kernel(
        int N, const float* __restrict__ x,
        const float* __restrict__ S1, const float* __restrict__ D1,
        const float* __restrict__ W1, const float* __restrict__ b1,
        const float* __restrict__ W2,
        const float* __restrict__ denom1, const float* __restrict__ num1,
        float* __restrict__ h2out) {
    int n = blockIdx.x * blockDim.x + threadIdx.x;
    if (n >= N) return;
    float xn = x[n];
    float acc = 0.f;
#pragma unroll
    for (int h = 0; h < NHEADS; ++h) {
        // self-loop edge (n -> n)
        float e = xn * (S1[h] + D1[h]);
        e = e > 0.f ? e : NEG_SLOPE * e;
        float ex = __expf(e);
        float den = denom1[(size_t)n * NHEADS + h] + ex + EPSV;
        float num = num1[(size_t)n * NHEADS + h] + ex * xn;
        float z = num / den;
#pragma unroll
        for (int c = 0; c < NCH; ++c) {
            int k = h * NCH + c;
            float v = W1[k] * z + b1[k];
            v = v > 0.f ? v : (__expf(v) - 1.f);   // elu
            acc += v * W2[k];
        }
    }
    h2out[n] = acc;
}

// Layer 2 edge pass (single head, scalar channel).
__global__ __launch_bounds__(256) void gat_edge2_kernel(
        const int* __restrict__ ei, int E, const float* __restrict__ h2,
        const float* __restrict__ as2p, const float* __restrict__ ad2p,
        float* __restrict__ denom2, float* __restrict__ num2) {
    int i = blockIdx.x * blockDim.x + threadIdx.x;
    if (i >= E) return;
    int s = ei[i];
    int d = ei[E + i];
    float hs = h2[s];
    float hd = h2[d];
    float e = hs * as2p[0] + hd * ad2p[0];
    e = e > 0.f ? e : NEG_SLOPE * e;
    float ex = __expf(e);
    atomicAdd(&denom2[d], ex);
    atomicAdd(&num2[d], ex * hs);
}

// Layer 2 node pass: fold in self-loop, out[n] = num/(denom+eps) + b2.
__global__ __launch_bounds__(256) void gat_node2_kernel(
        int N, const float* __restrict__ h2,
        const float* __restrict__ as2p, const float* __restrict__ ad2p,
        const float* __restrict__ b2,
        const float* __restrict__ denom2, const float* __restrict__ num2,
        float* __restrict__ out) {
    int n = blockIdx.x * blockDim.x + threadIdx.x;
    if (n >= N) return;
    float hn = h2[n];
    float e = hn * (as2p[0] + ad2p[0]);
    e = e > 0.f ? e : NEG_SLOPE * e;
    float ex = __expf(e);
    float den = denom2[n] + ex + EPSV;
    float num = num2[n] + ex * hn;
    out[n] = num / den + b2[0];
}

extern "C" void kernel_launch(void* const* d_in, const int* in_sizes, int n_in,
                              void* d_out, int out_size, void* d_ws, size_t ws_size,
                              hipStream_t stream) {
    const float* x   = (const float*)d_in[0];
    const int*   ei  = (const int*)d_in[1];
    const float* W1  = (const float*)d_in[2];
    const float* as1 = (const float*)d_in[3];
    const float* ad1 = (const float*)d_in[4];
    const float* b1  = (const float*)d_in[5];
    const float* W2  = (const float*)d_in[6];
    const float* as2 = (const float*)d_in[7];
    const float* ad2 = (const float*)d_in[8];
    const float* b2  = (const float*)d_in[9];
    float* out = (float*)d_out;

    int N = in_sizes[0];       // 100000 (x is (N,1))
    int E = in_sizes[1] / 2;   // 1600000

    // Workspace layout (floats): S1[8] | D1[8] | h2[N] | denom1[N*8] |
    // num1[N*8] | denom2[N] | num2[N]
    float* f      = (float*)d_ws;
    float* S1     = f;
    float* D1     = f + 8;
    float* h2     = f + 16;
    float* denom1 = h2 + N;
    float* num1   = denom1 + (size_t)N * NHEADS;
    float* denom2 = num1 + (size_t)N * NHEADS;
    float* num2   = denom2 + N;

    // Zero the accumulators (denom1, num1, denom2, num2 are contiguous).
    size_t zero_bytes = ((size_t)N * NHEADS * 2 + (size_t)N * 2) * sizeof(float);
    hipMemsetAsync(denom1, 0, zero_bytes, stream);

    gat_setup_kernel<<<1, NHEADS, 0, stream>>>(W1, as1, ad1, S1, D1);

    int eb = (E + 255) / 256;
    int nb = (N + 255) / 256;

    gat_edge1_kernel<<<eb, 256, 0, stream>>>(ei, E, x, S1, D1, denom1, num1);
    gat_node1_kernel<<<nb, 256, 0, stream>>>(N, x, S1, D1, W1, b1, W2,
                                             denom1, num1, h2);
    gat_edge2_kernel<<<eb, 256, 0, stream>>>(ei, E, h2, as2, ad2, denom2, num2);
    gat_node2_kernel<<<nb, 256, 0, stream>>>(N, h2, as2, ad2, b2,
                                             denom2, num2, out);
}

// Round 2
// 526.168 us; speedup vs baseline: 2.8977x; 2.8977x over previous
//
#include <hip/hip_runtime.h>

#define NEG_SLOPE 0.2f
#define EPSV 1e-16f
#define NHEADS 8
#define NCH 16

// S1[h] = sum_c W1[h*16+c]*att_src1[h*16+c]; D1 likewise with att_dst1.
__global__ void gat_setup_kernel(const float* __restrict__ W1,
                                 const float* __restrict__ as1,
                                 const float* __restrict__ ad1,
                                 float* __restrict__ S1, float* __restrict__ D1) {
    int h = threadIdx.x;
    if (h < NHEADS) {
        float s = 0.f, d = 0.f;
        for (int c = 0; c < NCH; ++c) {
            float w = W1[h * NCH + c];
            s += w * as1[h * NCH + c];
            d += w * ad1[h * NCH + c];
        }
        S1[h] = s;
        D1[h] = d;
    }
}

// Histogram of dst: cc[d]++ per edge. cc must be zeroed beforehand.
__global__ __launch_bounds__(256) void gat_hist_kernel(
        const int* __restrict__ ei, int E, int* __restrict__ cc) {
    int i = blockIdx.x * blockDim.x + threadIdx.x;
    if (i >= E) return;
    atomicAdd(&cc[ei[E + i]], 1);
}

// Single-block exclusive scan over N counts. On exit:
//   row_start[n] = exclusive prefix; cc[n] = same value (scatter cursor).
__global__ __launch_bounds__(1024) void gat_scan_kernel(
        int N, int* __restrict__ cc, int* __restrict__ row_start) {
    __shared__ int sums[1024];
    int t = threadIdx.x;
    int chunk = (N + 1023) >> 10;
    int lo = t * chunk;
    int hi = lo + chunk; if (hi > N) hi = N;
    int s = 0;
    for (int i = lo; i < hi; ++i) s += cc[i];
    sums[t] = s;
    __syncthreads();
    for (int off = 1; off < 1024; off <<= 1) {
        int tmp = (t >= off) ? sums[t - off] : 0;
        __syncthreads();
        sums[t] += tmp;
        __syncthreads();
    }
    int run = sums[t] - s;   // exclusive prefix of this thread's chunk
    for (int i = lo; i < hi; ++i) {
        int c = cc[i];
        row_start[i] = run;
        cc[i] = run;
        run += c;
    }
}

// Scatter edges into CSR order: csr_src[pos] = src, grouped by dst.
// After this, cc[n] == row_end[n].
__global__ __launch_bounds__(256) void gat_scatter_kernel(
        const int* __restrict__ ei, int E, int* __restrict__ cc,
        int* __restrict__ csr_src) {
    int i = blockIdx.x * blockDim.x + threadIdx.x;
    if (i >= E) return;
    int s = ei[i];
    int d = ei[E + i];
    int pos = atomicAdd(&cc[d], 1);
    csr_src[pos] = s;
}

// Layer 1: per-node gather over incoming edges, all 8 heads in registers,
// fold self-loop, then z -> elu(W1*z+b1) -> dot W2 -> h2[n].
__global__ __launch_bounds__(256) void gat_gather1_kernel(
        int N, const float* __restrict__ x,
        const int* __restrict__ row_start, const int* __restrict__ row_end,
        const int* __restrict__ csr_src,
        const float* __restrict__ S1g, const float* __restrict__ D1g,
        const float* __restrict__ W1, const float* __restrict__ b1,
        const float* __restrict__ W2,
        float* __restrict__ h2out) {
    int n = blockIdx.x * blockDim.x + threadIdx.x;
    if (n >= N) return;
    float xn = x[n];
    float S1[NHEADS], A[NHEADS], den[NHEADS], num[NHEADS];
#pragma unroll
    for (int h = 0; h < NHEADS; ++h) {
        S1[h] = S1g[h];
        A[h] = xn * D1g[h];            // dst-side contribution, fixed per node
        // self-loop edge (n -> n)
        float e = xn * S1[h] + A[h];
        e = e > 0.f ? e : NEG_SLOPE * e;
        float ex = __expf(e);
        den[h] = ex + EPSV;
        num[h] = ex * xn;
    }
    int lo = row_start[n], hi = row_end[n];
    for (int j = lo; j < hi; ++j) {
        float xs = x[csr_src[j]];
#pragma unroll
        for (int h = 0; h < NHEADS; ++h) {
            float e = xs * S1[h] + A[h];
            e = e > 0.f ? e : NEG_SLOPE * e;
            float ex = __expf(e);
            den[h] += ex;
            num[h] += ex * xs;
        }
    }
    float acc = 0.f;
#pragma unroll
    for (int h = 0; h < NHEADS; ++h) {
        float z = num[h] / den[h];
#pragma unroll
        for (int c = 0; c < NCH; ++c) {
            int k = h * NCH + c;
            float v = W1[k] * z + b1[k];
            v = v > 0.f ? v : (__expf(v) - 1.f);   // elu
            acc += v * W2[k];
        }
    }
    h2out[n] = acc;
}

// Layer 2: single head/channel gather over the same CSR.
__global__ __launch_bounds__(256) void gat_gather2_kernel(
        int N, const float* __restrict__ h2,
        const int* __restrict__ row_start, const int* __restrict__ row_end,
        const int* __restrict__ csr_src,
        const float* __restrict__ as2p, const float* __restrict__ ad2p,
        const float* __restrict__ b2,
        float* __restrict__ out) {
    int n = blockIdx.x * blockDim.x + threadIdx.x;
    if (n >= N) return;
    float a_s = as2p[0], a_d = ad2p[0];
    float hn = h2[n];
    float ad = hn * a_d;
    // self-loop
    float e = hn * a_s + ad;
    e = e > 0.f ? e : NEG_SLOPE * e;
    float ex = __expf(e);
    float den = ex + EPSV;
    float num = ex * hn;
    int lo = row_start[n], hi = row_end[n];
    for (int j = lo; j < hi; ++j) {
        float hs = h2[csr_src[j]];
        float ee = hs * a_s + ad;
        ee = ee > 0.f ? ee : NEG_SLOPE * ee;
        float exx = __expf(ee);
        den += exx;
        num += exx * hs;
    }
    out[n] = num / den + b2[0];
}

extern "C" void kernel_launch(void* const* d_in, const int* in_sizes, int n_in,
                              void* d_out, int out_size, void* d_ws, size_t ws_size,
                              hipStream_t stream) {
    const float* x   = (const float*)d_in[0];
    const int*   ei  = (const int*)d_in[1];
    const float* W1  = (const float*)d_in[2];
    const float* as1 = (const float*)d_in[3];
    const float* ad1 = (const float*)d_in[4];
    const float* b1  = (const float*)d_in[5];
    const float* W2  = (const float*)d_in[6];
    const float* as2 = (const float*)d_in[7];
    const float* ad2 = (const float*)d_in[8];
    const float* b2  = (const float*)d_in[9];
    float* out = (float*)d_out;

    int N = in_sizes[0];       // 100000
    int E = in_sizes[1] / 2;   // 1600000

    // Workspace layout: S1[8]f | D1[8]f | h2[N]f | row_start[N]i | cc[N]i |
    // csr_src[E]i   (total ~7.6 MB)
    float* S1        = (float*)d_ws;
    float* D1        = S1 + 8;
    float* h2        = D1 + 8;
    int*   row_start = (int*)(h2 + N);
    int*   cc        = row_start + N;   // histogram -> cursor -> row_end
    int*   csr_src   = cc + N;

    hipMemsetAsync(cc, 0, (size_t)N * sizeof(int), stream);

    gat_setup_kernel<<<1, NHEADS, 0, stream>>>(W1, as1, ad1, S1, D1);

    int eb = (E + 255) / 256;
    int nb = (N + 255) / 256;

    gat_hist_kernel<<<eb, 256, 0, stream>>>(ei, E, cc);
    gat_scan_kernel<<<1, 1024, 0, stream>>>(N, cc, row_start);
    gat_scatter_kernel<<<eb, 256, 0, stream>>>(ei, E, cc, csr_src);
    // after scatter: cc[n] == row_end[n]
    gat_gather1_kernel<<<nb, 256, 0, stream>>>(N, x, row_start, cc, csr_src,
                                               S1, D1, W1, b1, W2, h2);
    gat_gather2_kernel<<<nb, 256, 0, stream>>>(N, h2, row_start, cc, csr_src,
                                               as2, ad2, b2, out);
}

// Round 3
// 319.687 us; speedup vs baseline: 4.7692x; 1.6459x over previous
//
#include <hip/hip_runtime.h>

#define NEG_SLOPE 0.2f
#define EPSV 1e-16f
#define NHEADS 8
#define NCH 16
#define SCAN_TILE 1024   // 256 threads x 4 elements

// S1[h] = sum_c W1[h*16+c]*att_src1[h*16+c]; D1 likewise with att_dst1.
__global__ void gat_setup_kernel(const float* __restrict__ W1,
                                 const float* __restrict__ as1,
                                 const float* __restrict__ ad1,
                                 float* __restrict__ S1, float* __restrict__ D1) {
    int h = threadIdx.x;
    if (h < NHEADS) {
        float s = 0.f, d = 0.f;
        for (int c = 0; c < NCH; ++c) {
            float w = W1[h * NCH + c];
            s += w * as1[h * NCH + c];
            d += w * ad1[h * NCH + c];
        }
        S1[h] = s;
        D1[h] = d;
    }
}

// Histogram of dst: cc[d]++ per edge. cc must be zeroed beforehand.
__global__ __launch_bounds__(256) void gat_hist_kernel(
        const int* __restrict__ ei, int E, int* __restrict__ cc) {
    int i = blockIdx.x * blockDim.x + threadIdx.x;
    if (i >= E) return;
    atomicAdd(&cc[ei[E + i]], 1);
}

// Scan phase A: per-block tile sums.
__global__ __launch_bounds__(256) void gat_scan_a_kernel(
        const int* __restrict__ cc, int N, int* __restrict__ bsum) {
    int b = blockIdx.x, t = threadIdx.x;
    int base = b * SCAN_TILE + t * 4;
    int s = 0;
    if (base + 3 < N) {
        int4 v = *(const int4*)(cc + base);
        s = v.x + v.y + v.z + v.w;
    } else {
        for (int k = 0; k < 4; ++k) if (base + k < N) s += cc[base + k];
    }
    __shared__ int red[256];
    red[t] = s;
    __syncthreads();
    for (int off = 128; off > 0; off >>= 1) {
        if (t < off) red[t] += red[t + off];
        __syncthreads();
    }
    if (t == 0) bsum[b] = red[0];
}

// Scan phase B: single block exclusive-scans up to 256 block sums in place.
__global__ __launch_bounds__(256) void gat_scan_b_kernel(
        int* __restrict__ bsum, int nb) {
    __shared__ int sh[256];
    int t = threadIdx.x;
    int v = (t < nb) ? bsum[t] : 0;
    sh[t] = v;
    __syncthreads();
    for (int off = 1; off < 256; off <<= 1) {
        int tmp = (t >= off) ? sh[t - off] : 0;
        __syncthreads();
        sh[t] += tmp;
        __syncthreads();
    }
    if (t < nb) bsum[t] = sh[t] - v;   // exclusive
}

// Scan phase C: per-block exclusive scan + global offset. Reads cc (counts),
// writes row_start[i] and cc[i] (in place) = exclusive prefix (scatter cursor).
__global__ __launch_bounds__(256) void gat_scan_c_kernel(
        int* __restrict__ cc, int N, const int* __restrict__ bsum,
        int* __restrict__ row_start) {
    int b = blockIdx.x, t = threadIdx.x;
    int base = b * SCAN_TILE + t * 4;
    int v0 = 0, v1 = 0, v2 = 0, v3 = 0;
    bool full = (base + 3 < N);
    if (full) {
        int4 q = *(const int4*)(cc + base);
        v0 = q.x; v1 = q.y; v2 = q.z; v3 = q.w;
    } else {
        if (base + 0 < N) v0 = cc[base + 0];
        if (base + 1 < N) v1 = cc[base + 1];
        if (base + 2 < N) v2 = cc[base + 2];
        if (base + 3 < N) v3 = cc[base + 3];
    }
    int s = v0 + v1 + v2 + v3;
    __shared__ int sh[256];
    sh[t] = s;
    __syncthreads();
    for (int off = 1; off < 256; off <<= 1) {
        int tmp = (t >= off) ? sh[t - off] : 0;
        __syncthreads();
        sh[t] += tmp;
        __syncthreads();
    }
    int run = bsum[b] + sh[t] - s;   // exclusive prefix of this thread's quad
    int o0 = run; run += v0;
    int o1 = run; run += v1;
    int o2 = run; run += v2;
    int o3 = run;
    if (full) {
        *(int4*)(row_start + base) = make_int4(o0, o1, o2, o3);
        *(int4*)(cc + base)        = make_int4(o0, o1, o2, o3);
    } else {
        if (base + 0 < N) { row_start[base + 0] = o0; cc[base + 0] = o0; }
        if (base + 1 < N) { row_start[base + 1] = o1; cc[base + 1] = o1; }
        if (base + 2 < N) { row_start[base + 2] = o2; cc[base + 2] = o2; }
        if (base + 3 < N) { row_start[base + 3] = o3; cc[base + 3] = o3; }
    }
}

// Scatter edges into CSR order: csr_src[pos] = src, grouped by dst.
// After this, cc[n] == row_end[n].
__global__ __launch_bounds__(256) void gat_scatter_kernel(
        const int* __restrict__ ei, int E, int* __restrict__ cc,
        int* __restrict__ csr_src) {
    int i = blockIdx.x * blockDim.x + threadIdx.x;
    if (i >= E) return;
    int s = ei[i];
    int d = ei[E + i];
    int pos = atomicAdd(&cc[d], 1);
    csr_src[pos] = s;
}

// Layer 1: per-node gather over incoming edges, all 8 heads in registers,
// fold self-loop, then z -> elu(W1*z+b1) -> dot W2 -> h2[n].
__global__ __launch_bounds__(256) void gat_gather1_kernel(
        int N, const float* __restrict__ x,
        const int* __restrict__ row_start, const int* __restrict__ row_end,
        const int* __restrict__ csr_src,
        const float* __restrict__ S1g, const float* __restrict__ D1g,
        const float* __restrict__ W1, const float* __restrict__ b1,
        const float* __restrict__ W2,
        float* __restrict__ h2out) {
    int n = blockIdx.x * blockDim.x + threadIdx.x;
    if (n >= N) return;
    float xn = x[n];
    float S1[NHEADS], A[NHEADS], den[NHEADS], num[NHEADS];
#pragma unroll
    for (int h = 0; h < NHEADS; ++h) {
        S1[h] = S1g[h];
        A[h] = xn * D1g[h];            // dst-side contribution, fixed per node
        // self-loop edge (n -> n)
        float e = xn * S1[h] + A[h];
        e = e > 0.f ? e : NEG_SLOPE * e;
        float ex = __expf(e);
        den[h] = ex + EPSV;
        num[h] = ex * xn;
    }
    int lo = row_start[n], hi = row_end[n];
    for (int j = lo; j < hi; ++j) {
        float xs = x[csr_src[j]];
#pragma unroll
        for (int h = 0; h < NHEADS; ++h) {
            float e = xs * S1[h] + A[h];
            e = e > 0.f ? e : NEG_SLOPE * e;
            float ex = __expf(e);
            den[h] += ex;
            num[h] += ex * xs;
        }
    }
    float acc = 0.f;
#pragma unroll
    for (int h = 0; h < NHEADS; ++h) {
        float z = num[h] / den[h];
#pragma unroll
        for (int c = 0; c < NCH; ++c) {
            int k = h * NCH + c;
            float v = W1[k] * z + b1[k];
            v = v > 0.f ? v : (__expf(v) - 1.f);   // elu
            acc += v * W2[k];
        }
    }
    h2out[n] = acc;
}

// Layer 2: single head/channel gather over the same CSR.
__global__ __launch_bounds__(256) void gat_gather2_kernel(
        int N, const float* __restrict__ h2,
        const int* __restrict__ row_start, const int* __restrict__ row_end,
        const int* __restrict__ csr_src,
        const float* __restrict__ as2p, const float* __restrict__ ad2p,
        const float* __restrict__ b2,
        float* __restrict__ out) {
    int n = blockIdx.x * blockDim.x + threadIdx.x;
    if (n >= N) return;
    float a_s = as2p[0], a_d = ad2p[0];
    float hn = h2[n];
    float ad = hn * a_d;
    // self-loop
    float e = hn * a_s + ad;
    e = e > 0.f ? e : NEG_SLOPE * e;
    float ex = __expf(e);
    float den = ex + EPSV;
    float num = ex * hn;
    int lo = row_start[n], hi = row_end[n];
    for (int j = lo; j < hi; ++j) {
        float hs = h2[csr_src[j]];
        float ee = hs * a_s + ad;
        ee = ee > 0.f ? ee : NEG_SLOPE * ee;
        float exx = __expf(ee);
        den += exx;
        num += exx * hs;
    }
    out[n] = num / den + b2[0];
}

extern "C" void kernel_launch(void* const* d_in, const int* in_sizes, int n_in,
                              void* d_out, int out_size, void* d_ws, size_t ws_size,
                              hipStream_t stream) {
    const float* x   = (const float*)d_in[0];
    const int*   ei  = (const int*)d_in[1];
    const float* W1  = (const float*)d_in[2];
    const float* as1 = (const float*)d_in[3];
    const float* ad1 = (const float*)d_in[4];
    const float* b1  = (const float*)d_in[5];
    const float* W2  = (const float*)d_in[6];
    const float* as2 = (const float*)d_in[7];
    const float* ad2 = (const float*)d_in[8];
    const float* b2  = (const float*)d_in[9];
    float* out = (float*)d_out;

    int N = in_sizes[0];       // 100000
    int E = in_sizes[1] / 2;   // 1600000

    int nscan = (N + SCAN_TILE - 1) / SCAN_TILE;   // 98 for N=100000

    // Workspace layout: S1[8]f | D1[8]f | h2[N]f | row_start[N]i | cc[N]i |
    // csr_src[E]i | bsum[nscan]i
    float* S1        = (float*)d_ws;
    float* D1        = S1 + 8;
    float* h2        = D1 + 8;
    int*   row_start = (int*)(h2 + N);
    int*   cc        = row_start + N;   // histogram -> cursor -> row_end
    int*   csr_src   = cc + N;
    int*   bsum      = csr_src + E;

    hipMemsetAsync(cc, 0, (size_t)N * sizeof(int), stream);

    gat_setup_kernel<<<1, NHEADS, 0, stream>>>(W1, as1, ad1, S1, D1);

    int eb = (E + 255) / 256;
    int nb = (N + 255) / 256;

    gat_hist_kernel<<<eb, 256, 0, stream>>>(ei, E, cc);
    gat_scan_a_kernel<<<nscan, 256, 0, stream>>>(cc, N, bsum);
    gat_scan_b_kernel<<<1, 256, 0, stream>>>(bsum, nscan);
    gat_scan_c_kernel<<<nscan, 256, 0, stream>>>(cc, N, bsum, row_start);
    gat_scatter_kernel<<<eb, 256, 0, stream>>>(ei, E, cc, csr_src);
    // after scatter: cc[n] == row_end[n]
    gat_gather1_kernel<<<nb, 256, 0, stream>>>(N, x, row_start, cc, csr_src,
                                               S1, D1, W1, b1, W2, h2);
    gat_gather2_kernel<<<nb, 256, 0, stream>>>(N, h2, row_start, cc, csr_src,
                                               as2, ad2, b2, out);
}